// Round 1
// baseline (1824.966 us; speedup 1.0000x reference)
//
#include <hip/hip_runtime.h>

#define WAVE 64

__device__ __forceinline__ float lrelu(float v, float s) { return v > 0.f ? v : v * s; }

// monotone float<->uint encoding for atomicMax on floats
__device__ __forceinline__ unsigned int fenc(float f) {
    unsigned int u = __float_as_uint(f);
    return (u & 0x80000000u) ? ~u : (u | 0x80000000u);
}
__device__ __forceinline__ float fdec(unsigned int u) {
    u = (u & 0x80000000u) ? (u & 0x7FFFFFFFu) : ~u;
    return __uint_as_float(u);
}

// edge index load that handles int32 or int64 storage (flag from detect kernel)
__device__ __forceinline__ int ld_idx(const int* p, int e, int is64) {
    return is64 ? (int)(((const long long*)p)[e]) : p[e];
}

__global__ void detect_i64(const unsigned int* idx, int* flag) {
    if (blockIdx.x == 0 && threadIdx.x == 0) {
        int all0 = 1;
        for (int i = 1; i < 256; i += 2) {
            if (idx[i] != 0u) { all0 = 0; break; }
        }
        *flag = all0;
    }
}

// ---------------- tiled fp32 GEMM: C[M,N] = A[M,K] @ B[K,N] + bias[N] ----------------
#define BM 64
#define BN 64
#define BK 16
__global__ __launch_bounds__(256) void gemm_bias(
    const float* __restrict__ A, const float* __restrict__ B,
    const float* __restrict__ bias, float* __restrict__ C,
    int M, int N, int K, int do_lrelu, float slope)
{
    __shared__ float As[BK][BM + 1];
    __shared__ float Bs[BK][BN + 1];
    int tid = threadIdx.x;
    int tx = tid & 15, ty = tid >> 4;
    int bm = blockIdx.x * BM, bn = blockIdx.y * BN;
    float acc[4][4] = {};
    for (int k0 = 0; k0 < K; k0 += BK) {
#pragma unroll
        for (int i = 0; i < 4; i++) {
            int idx = tid + i * 256;        // 0..1023
            int r = idx / BK, c = idx % BK; // A tile row/col
            int gr = bm + r;
            As[c][r] = (gr < M) ? A[(long long)gr * K + (k0 + c)] : 0.f;
        }
#pragma unroll
        for (int i = 0; i < 4; i++) {
            int idx = tid + i * 256;
            int r = idx / BN, c = idx % BN;
            Bs[r][c] = B[(long long)(k0 + r) * N + (bn + c)];
        }
        __syncthreads();
#pragma unroll
        for (int kk = 0; kk < BK; kk++) {
            float a[4], b[4];
#pragma unroll
            for (int i = 0; i < 4; i++) a[i] = As[kk][ty * 4 + i];
#pragma unroll
            for (int j = 0; j < 4; j++) b[j] = Bs[kk][tx * 4 + j];
#pragma unroll
            for (int i = 0; i < 4; i++)
#pragma unroll
                for (int j = 0; j < 4; j++) acc[i][j] += a[i] * b[j];
        }
        __syncthreads();
    }
#pragma unroll
    for (int i = 0; i < 4; i++) {
        int gr = bm + ty * 4 + i;
        if (gr >= M) continue;
#pragma unroll
        for (int j = 0; j < 4; j++) {
            int gc = bn + tx * 4 + j;
            float v = acc[i][j] + bias[gc];
            if (do_lrelu) v = lrelu(v, slope);
            C[(long long)gr * N + gc] = v;
        }
    }
}

// ---------------- edge phase kernels (C=64 channels == lanes) ----------------
// one wave per (edge, head): score = sum_c lrelu(xl[s]+xr[d],0.2)*att ; atomicMax of score per (d,h)
template <int H>
__global__ __launch_bounds__(256) void edge_score(
    const float* __restrict__ xl, const float* __restrict__ xr,
    const float* __restrict__ att, const int* __restrict__ eidx,
    const int* __restrict__ flagp, int E, int n,
    float* __restrict__ score, unsigned int* __restrict__ mmax)
{
    long long gw = ((long long)blockIdx.x * blockDim.x + threadIdx.x) >> 6;
    int lane = threadIdx.x & 63;
    long long items = (long long)(E + n) * H;
    if (gw >= items) return;
    int e = (int)(gw / H);
    int h = (int)(gw % H);
    int is64 = *flagp;
    int s, d;
    if (e < E) { s = ld_idx(eidx, e, is64); d = ld_idx(eidx, E + e, is64); }
    else { s = e - E; d = s; }
    float a = xl[s * (H * 64) + h * 64 + lane];
    float b = xr[d * (H * 64) + h * 64 + lane];
    float v = lrelu(a + b, 0.2f) * att[h * 64 + lane];
#pragma unroll
    for (int off = 32; off; off >>= 1) v += __shfl_xor(v, off);
    if (lane == 0) {
        score[gw] = v;
        atomicMax(&mmax[d * H + h], fenc(v));
    }
}

// one thread per (edge, head): e = exp(score - m[d]); score <- e; atomicAdd sum
template <int H>
__global__ void edge_expsum(
    const int* __restrict__ eidx, const int* __restrict__ flagp, int E, int n,
    const unsigned int* __restrict__ mmax, float* __restrict__ score,
    float* __restrict__ ssum)
{
    long long t = (long long)blockIdx.x * blockDim.x + threadIdx.x;
    long long items = (long long)(E + n) * H;
    if (t >= items) return;
    int e = (int)(t / H);
    int h = (int)(t % H);
    int is64 = *flagp;
    int d = (e < E) ? ld_idx(eidx, E + e, is64) : (e - E);
    float m = fdec(mmax[d * H + h]);
    float ev = expf(score[t] - m);
    score[t] = ev;
    atomicAdd(&ssum[d * H + h], ev);
}

// one wave per (edge, head): out[d] += (e/(s+eps)) * xl[s]
template <int H>
__global__ __launch_bounds__(256) void edge_agg(
    const float* __restrict__ xl, const int* __restrict__ eidx,
    const int* __restrict__ flagp, int E, int n,
    const float* __restrict__ score, const float* __restrict__ ssum,
    float* __restrict__ acc)
{
    long long gw = ((long long)blockIdx.x * blockDim.x + threadIdx.x) >> 6;
    int lane = threadIdx.x & 63;
    long long items = (long long)(E + n) * H;
    if (gw >= items) return;
    int e = (int)(gw / H);
    int h = (int)(gw % H);
    int is64 = *flagp;
    int s, d;
    if (e < E) { s = ld_idx(eidx, e, is64); d = ld_idx(eidx, E + e, is64); }
    else { s = e - E; d = s; }
    float alpha = score[gw] / (ssum[d * H + h] + 1e-16f);
    atomicAdd(&acc[d * (H * 64) + h * 64 + lane], alpha * xl[s * (H * 64) + h * 64 + lane]);
}

// elementwise: buf += bias (broadcast over rows), optional leaky-relu
__global__ void bias_act(float* __restrict__ buf, const float* __restrict__ bias,
                         int rowlen, long long total, int do_lrelu, float slope)
{
    long long i = (long long)blockIdx.x * blockDim.x + threadIdx.x;
    if (i >= total) return;
    float v = buf[i] + bias[(int)(i % rowlen)];
    if (do_lrelu) v = lrelu(v, slope);
    buf[i] = v;
}

// fused predict head: logits = leaky(h2@Wp1+bp1,0.01)@Wp2+bp2, one thread per node
__global__ void predict_head(const float* __restrict__ h2,
                             const float* __restrict__ Wp1, const float* __restrict__ bp1,
                             const float* __restrict__ Wp2, const float* __restrict__ bp2,
                             float* __restrict__ logits, int n)
{
    int i = blockIdx.x * blockDim.x + threadIdx.x;
    if (i >= n) return;
    float h[64];
#pragma unroll
    for (int c = 0; c < 64; c++) h[c] = h2[(long long)i * 64 + c];
    float logit = bp2[0];
#pragma unroll
    for (int j = 0; j < 32; j++) {
        float z = bp1[j];
#pragma unroll
        for (int c = 0; c < 64; c++) z += h[c] * Wp1[c * 32 + j];
        z = lrelu(z, 0.01f);
        logit += z * Wp2[j];
    }
    logits[i] = logit;
}

extern "C" void kernel_launch(void* const* d_in, const int* in_sizes, int n_in,
                              void* d_out, int out_size, void* d_ws, size_t ws_size,
                              hipStream_t stream)
{
    const float* x    = (const float*)d_in[0];
    const int*   eidx = (const int*)d_in[1];
    const float* W1l  = (const float*)d_in[2];
    const float* b1l  = (const float*)d_in[3];
    const float* W1r  = (const float*)d_in[4];
    const float* b1r  = (const float*)d_in[5];
    const float* att1 = (const float*)d_in[6];
    const float* bias1= (const float*)d_in[7];
    const float* W2l  = (const float*)d_in[8];
    const float* b2l  = (const float*)d_in[9];
    const float* W2r  = (const float*)d_in[10];
    const float* b2r  = (const float*)d_in[11];
    const float* att2 = (const float*)d_in[12];
    const float* bias2= (const float*)d_in[13];
    const float* Wp1  = (const float*)d_in[14];
    const float* bp1  = (const float*)d_in[15];
    const float* Wp2  = (const float*)d_in[16];
    const float* bp2  = (const float*)d_in[17];

    const int n = in_sizes[0] / 256;  // 50000
    const int E = in_sizes[1] / 2;    // 600000
    const int Etot = E + n;

    float* out = (float*)d_out;       // [0,n): logits ; [n, n+n*64): h
    float* ws  = (float*)d_ws;

    // workspace layout (floats)
    float*        xl1   = ws;
    float*        xr1   = xl1 + (size_t)n * 256;
    float*        h1    = xr1 + (size_t)n * 256;
    float*        sc1   = h1  + (size_t)n * 256;         // Etot*4
    unsigned int* m1    = (unsigned int*)(sc1 + (size_t)Etot * 4); // n*4
    float*        s1    = (float*)(m1 + (size_t)n * 4);  // n*4
    int*          flagp = (int*)(s1 + (size_t)n * 4);
    float*        xl2   = xl1;          // reuse after layer-1 edge phase
    float*        xr2   = xl1 + (size_t)n * 64;
    float*        sc2   = sc1;
    unsigned int* m2    = m1;
    float*        s2    = s1;
    float*        h2    = out + n;      // layer-2 output lives in d_out

    detect_i64<<<1, 64, 0, stream>>>((const unsigned int*)eidx, flagp);

    // ---- layer 1 projections ----
    {
        dim3 grid((n + BM - 1) / BM, 256 / BN);
        gemm_bias<<<grid, 256, 0, stream>>>(x, W1l, b1l, xl1, n, 256, 256, 0, 0.f);
        gemm_bias<<<grid, 256, 0, stream>>>(x, W1r, b1r, xr1, n, 256, 256, 0, 0.f);
    }

    hipMemsetAsync(m1, 0, (size_t)n * 4 * sizeof(unsigned int), stream);
    hipMemsetAsync(s1, 0, (size_t)n * 4 * sizeof(float), stream);
    hipMemsetAsync(h1, 0, (size_t)n * 256 * sizeof(float), stream);

    // ---- layer 1 edge phase ----
    {
        long long items = (long long)Etot * 4;
        int wblocks = (int)((items + 3) / 4);                 // 4 waves per 256-thread block
        int tblocks = (int)((items + 255) / 256);
        edge_score<4><<<wblocks, 256, 0, stream>>>(xl1, xr1, att1, eidx, flagp, E, n, sc1, m1);
        edge_expsum<4><<<tblocks, 256, 0, stream>>>(eidx, flagp, E, n, m1, sc1, s1);
        edge_agg<4><<<wblocks, 256, 0, stream>>>(xl1, eidx, flagp, E, n, sc1, s1, h1);
        long long tot = (long long)n * 256;
        bias_act<<<(int)((tot + 255) / 256), 256, 0, stream>>>(h1, bias1, 256, tot, 1, 0.01f);
    }

    // ---- layer 2 projections ----
    {
        dim3 grid((n + BM - 1) / BM, 1);
        gemm_bias<<<grid, 256, 0, stream>>>(h1, W2l, b2l, xl2, n, 64, 256, 0, 0.f);
        gemm_bias<<<grid, 256, 0, stream>>>(h1, W2r, b2r, xr2, n, 64, 256, 0, 0.f);
    }

    hipMemsetAsync(m2, 0, (size_t)n * sizeof(unsigned int), stream);
    hipMemsetAsync(s2, 0, (size_t)n * sizeof(float), stream);
    hipMemsetAsync(h2, 0, (size_t)n * 64 * sizeof(float), stream);

    // ---- layer 2 edge phase ----
    {
        long long items = (long long)Etot;
        int wblocks = (int)((items + 3) / 4);
        int tblocks = (int)((items + 255) / 256);
        edge_score<1><<<wblocks, 256, 0, stream>>>(xl2, xr2, att2, eidx, flagp, E, n, sc2, m2);
        edge_expsum<1><<<tblocks, 256, 0, stream>>>(eidx, flagp, E, n, m2, sc2, s2);
        edge_agg<1><<<wblocks, 256, 0, stream>>>(xl2, eidx, flagp, E, n, sc2, s2, h2);
        long long tot = (long long)n * 64;
        bias_act<<<(int)((tot + 255) / 256), 256, 0, stream>>>(h2, bias2, 64, tot, 0, 0.f);
    }

    // ---- predict head ----
    predict_head<<<(n + 255) / 256, 256, 0, stream>>>(h2, Wp1, bp1, Wp2, bp2, out, n);
}

// Round 2
// 1044.050 us; speedup vs baseline: 1.7480x; 1.7480x over previous
//
#include <hip/hip_runtime.h>

__device__ __forceinline__ float lrelu(float v, float s) { return v > 0.f ? v : v * s; }

// edge index load that handles int32 or int64 storage (flag from detect kernel)
__device__ __forceinline__ int ld_idx(const int* p, int e, int is64) {
    return is64 ? (int)(((const long long*)p)[e]) : p[e];
}

__global__ void detect_i64(const unsigned int* idx, int* flag) {
    if (blockIdx.x == 0 && threadIdx.x == 0) {
        int all0 = 1;
        for (int i = 1; i < 256; i += 2) {
            if (idx[i] != 0u) { all0 = 0; break; }
        }
        *flag = all0;
    }
}

// ---------------- tiled fp32 GEMM: C[M,N] = A[M,K] @ B[K,N] + bias[N] ----------------
#define BM 64
#define BN 64
#define BK 16
__global__ __launch_bounds__(256) void gemm_bias(
    const float* __restrict__ A, const float* __restrict__ B,
    const float* __restrict__ bias, float* __restrict__ C,
    int M, int N, int K)
{
    __shared__ float As[BK][BM + 1];
    __shared__ float Bs[BK][BN + 1];
    int tid = threadIdx.x;
    int tx = tid & 15, ty = tid >> 4;
    int bm = blockIdx.x * BM, bn = blockIdx.y * BN;
    float acc[4][4] = {};
    for (int k0 = 0; k0 < K; k0 += BK) {
#pragma unroll
        for (int i = 0; i < 4; i++) {
            int idx = tid + i * 256;        // 0..1023
            int r = idx / BK, c = idx % BK; // A tile row/col
            int gr = bm + r;
            As[c][r] = (gr < M) ? A[(long long)gr * K + (k0 + c)] : 0.f;
        }
#pragma unroll
        for (int i = 0; i < 4; i++) {
            int idx = tid + i * 256;
            int r = idx / BN, c = idx % BN;
            Bs[r][c] = B[(long long)(k0 + r) * N + (bn + c)];
        }
        __syncthreads();
#pragma unroll
        for (int kk = 0; kk < BK; kk++) {
            float a[4], b[4];
#pragma unroll
            for (int i = 0; i < 4; i++) a[i] = As[kk][ty * 4 + i];
#pragma unroll
            for (int j = 0; j < 4; j++) b[j] = Bs[kk][tx * 4 + j];
#pragma unroll
            for (int i = 0; i < 4; i++)
#pragma unroll
                for (int j = 0; j < 4; j++) acc[i][j] += a[i] * b[j];
        }
        __syncthreads();
    }
#pragma unroll
    for (int i = 0; i < 4; i++) {
        int gr = bm + ty * 4 + i;
        if (gr >= M) continue;
#pragma unroll
        for (int j = 0; j < 4; j++) {
            int gc = bn + tx * 4 + j;
            C[(long long)gr * N + gc] = acc[i][j] + bias[gc];
        }
    }
}

// ---------------- CSR build (dst-sorted edge ids) ----------------
__global__ void hist_dst(const int* __restrict__ eidx, const int* __restrict__ flagp,
                         int E, int n, int* __restrict__ cnt)
{
    int t = blockIdx.x * blockDim.x + threadIdx.x;
    if (t >= E + n) return;
    int is64 = *flagp;
    int d = (t < E) ? ld_idx(eidx, E + t, is64) : (t - E);
    atomicAdd(&cnt[d], 1);
}

// single-workgroup chunked exclusive scan: rowptr[0..n] from cnt[0..n)
__global__ __launch_bounds__(1024) void scan_excl(const int* __restrict__ cnt,
                                                  int* __restrict__ rowptr, int n)
{
    __shared__ int buf[1024];
    __shared__ int carry_s;
    int tid = threadIdx.x;
    if (tid == 0) carry_s = 0;
    __syncthreads();
    for (int base = 0; base < n; base += 1024) {
        int i = base + tid;
        int v = (i < n) ? cnt[i] : 0;
        buf[tid] = v;
        __syncthreads();
        int acc = v;
        for (int off = 1; off < 1024; off <<= 1) {
            int t = (tid >= off) ? buf[tid - off] : 0;
            __syncthreads();
            acc += t;
            buf[tid] = acc;
            __syncthreads();
        }
        int carry = carry_s;
        if (i < n) rowptr[i] = carry + acc - v;
        __syncthreads();
        if (tid == 1023) carry_s = carry + acc;
        __syncthreads();
    }
    if (tid == 0) rowptr[n] = carry_s;
}

__global__ void scatter_edges(const int* __restrict__ eidx, const int* __restrict__ flagp,
                              int E, int n, const int* __restrict__ rowptr,
                              int* __restrict__ cursor, int* __restrict__ eord)
{
    int t = blockIdx.x * blockDim.x + threadIdx.x;
    if (t >= E + n) return;
    int is64 = *flagp;
    int d = (t < E) ? ld_idx(eidx, E + t, is64) : (t - E);
    int pos = atomicAdd(&cursor[d], 1);
    eord[rowptr[d] + pos] = t;
}

// ---------------- gather attention: one wave per (node, head), online softmax ----------------
template <int H>
__global__ __launch_bounds__(256) void node_attn(
    const float* __restrict__ xl, const float* __restrict__ xr,
    const float* __restrict__ att, const float* __restrict__ bias,
    const int* __restrict__ eidx, const int* __restrict__ flagp,
    const int* __restrict__ rowptr, const int* __restrict__ eord,
    int E, int n, float* __restrict__ out, int do_lrelu, float slope)
{
    int gw = (blockIdx.x * blockDim.x + threadIdx.x) >> 6;
    int lane = threadIdx.x & 63;
    if (gw >= n * H) return;
    int d = gw / H, h = gw - d * H;
    int is64 = *flagp;
    int beg = rowptr[d], end = rowptr[d + 1];
    float xrv = xr[(size_t)d * (H * 64) + h * 64 + lane];
    float attv = att[h * 64 + lane];
    float m = -1e30f, ssum = 0.f, o = 0.f;
    for (int i = beg; i < end; i++) {
        int e = eord[i];
        int s = (e < E) ? ld_idx(eidx, e, is64) : d;
        float xlv = xl[(size_t)s * (H * 64) + h * 64 + lane];
        float v = lrelu(xlv + xrv, 0.2f) * attv;
#pragma unroll
        for (int off = 32; off; off >>= 1) v += __shfl_xor(v, off);
        // v is now wave-uniform (full 64-lane sum)
        if (v > m) {
            float scale = __expf(m - v);
            ssum *= scale;
            o *= scale;
            m = v;
        }
        float ev = __expf(v - m);
        ssum += ev;
        o += ev * xlv;
    }
    float res = o / (ssum + 1e-16f) + bias[h * 64 + lane];
    if (do_lrelu) res = lrelu(res, slope);
    out[(size_t)d * (H * 64) + h * 64 + lane] = res;
}

// fused predict head: logits = leaky(h2@Wp1+bp1,0.01)@Wp2+bp2, one thread per node
__global__ void predict_head(const float* __restrict__ h2,
                             const float* __restrict__ Wp1, const float* __restrict__ bp1,
                             const float* __restrict__ Wp2, const float* __restrict__ bp2,
                             float* __restrict__ logits, int n)
{
    int i = blockIdx.x * blockDim.x + threadIdx.x;
    if (i >= n) return;
    float h[64];
#pragma unroll
    for (int c = 0; c < 64; c++) h[c] = h2[(long long)i * 64 + c];
    float logit = bp2[0];
#pragma unroll
    for (int j = 0; j < 32; j++) {
        float z = bp1[j];
#pragma unroll
        for (int c = 0; c < 64; c++) z += h[c] * Wp1[c * 32 + j];
        z = lrelu(z, 0.01f);
        logit += z * Wp2[j];
    }
    logits[i] = logit;
}

extern "C" void kernel_launch(void* const* d_in, const int* in_sizes, int n_in,
                              void* d_out, int out_size, void* d_ws, size_t ws_size,
                              hipStream_t stream)
{
    const float* x    = (const float*)d_in[0];
    const int*   eidx = (const int*)d_in[1];
    const float* W1l  = (const float*)d_in[2];
    const float* b1l  = (const float*)d_in[3];
    const float* W1r  = (const float*)d_in[4];
    const float* b1r  = (const float*)d_in[5];
    const float* att1 = (const float*)d_in[6];
    const float* bias1= (const float*)d_in[7];
    const float* W2l  = (const float*)d_in[8];
    const float* b2l  = (const float*)d_in[9];
    const float* W2r  = (const float*)d_in[10];
    const float* b2r  = (const float*)d_in[11];
    const float* att2 = (const float*)d_in[12];
    const float* bias2= (const float*)d_in[13];
    const float* Wp1  = (const float*)d_in[14];
    const float* bp1  = (const float*)d_in[15];
    const float* Wp2  = (const float*)d_in[16];
    const float* bp2  = (const float*)d_in[17];

    const int n = in_sizes[0] / 256;  // 50000
    const int E = in_sizes[1] / 2;    // 600000
    const int Etot = E + n;

    float* out = (float*)d_out;       // [0,n): logits ; [n, n+n*64): h
    float* ws  = (float*)d_ws;

    // workspace layout (floats)
    float* xl1   = ws;
    float* xr1   = xl1 + (size_t)n * 256;
    float* h1    = xr1 + (size_t)n * 256;
    int*   rowptr= (int*)(h1 + (size_t)n * 256);   // n+1
    int*   cnt   = rowptr + (n + 1);               // n (histogram, then cursor)
    int*   eord  = cnt + n;                        // Etot
    int*   flagp = eord + Etot;
    float* xl2   = xl1;                            // reuse after layer-1 edge phase
    float* xr2   = xl1 + (size_t)n * 64;
    float* h2    = out + n;                        // layer-2 output lives in d_out

    detect_i64<<<1, 64, 0, stream>>>((const unsigned int*)eidx, flagp);

    // ---- CSR build (shared by both layers) ----
    hipMemsetAsync(cnt, 0, (size_t)n * sizeof(int), stream);
    hist_dst<<<(Etot + 255) / 256, 256, 0, stream>>>(eidx, flagp, E, n, cnt);
    scan_excl<<<1, 1024, 0, stream>>>(cnt, rowptr, n);
    hipMemsetAsync(cnt, 0, (size_t)n * sizeof(int), stream);  // reuse as cursor
    scatter_edges<<<(Etot + 255) / 256, 256, 0, stream>>>(eidx, flagp, E, n, rowptr, cnt, eord);

    // ---- layer 1 projections ----
    {
        dim3 grid((n + BM - 1) / BM, 256 / BN);
        gemm_bias<<<grid, 256, 0, stream>>>(x, W1l, b1l, xl1, n, 256, 256);
        gemm_bias<<<grid, 256, 0, stream>>>(x, W1r, b1r, xr1, n, 256, 256);
    }

    // ---- layer 1 edge phase (gather, fused bias + leaky 0.01) ----
    {
        long long waves = (long long)n * 4;
        int blocks = (int)((waves * 64 + 255) / 256);
        node_attn<4><<<blocks, 256, 0, stream>>>(xl1, xr1, att1, bias1, eidx, flagp,
                                                 rowptr, eord, E, n, h1, 1, 0.01f);
    }

    // ---- layer 2 projections ----
    {
        dim3 grid((n + BM - 1) / BM, 1);
        gemm_bias<<<grid, 256, 0, stream>>>(h1, W2l, b2l, xl2, n, 64, 256);
        gemm_bias<<<grid, 256, 0, stream>>>(h1, W2r, b2r, xr2, n, 64, 256);
    }

    // ---- layer 2 edge phase ----
    {
        long long waves = (long long)n;
        int blocks = (int)((waves * 64 + 255) / 256);
        node_attn<1><<<blocks, 256, 0, stream>>>(xl2, xr2, att2, bias2, eidx, flagp,
                                                 rowptr, eord, E, n, h2, 0, 0.f);
    }

    // ---- predict head ----
    predict_head<<<(n + 255) / 256, 256, 0, stream>>>(h2, Wp1, bp1, Wp2, bp2, out, n);
}

// Round 3
// 756.377 us; speedup vs baseline: 2.4128x; 1.3803x over previous
//
#include <hip/hip_runtime.h>

typedef __attribute__((ext_vector_type(8))) __bf16 bf16x8;
typedef __attribute__((ext_vector_type(4))) float f32x4;

__device__ __forceinline__ float lrelu(float v, float s) { return v > 0.f ? v : v * s; }

__device__ __forceinline__ unsigned short f2bf(float f) {
    unsigned int u = __float_as_uint(f);
    u += 0x7FFFu + ((u >> 16) & 1u);
    return (unsigned short)(u >> 16);
}

// edge index load that handles int32 or int64 storage (flag from detect kernel)
__device__ __forceinline__ int ld_idx(const int* p, int e, int is64) {
    return is64 ? (int)(((const long long*)p)[e]) : p[e];
}

__global__ void detect_i64(const unsigned int* idx, int* flag) {
    if (blockIdx.x == 0 && threadIdx.x == 0) {
        int all0 = 1;
        for (int i = 1; i < 256; i += 2) {
            if (idx[i] != 0u) { all0 = 0; break; }
        }
        *flag = all0;
    }
}

// ---------------- conversion kernels ----------------
__global__ void f32_to_bf16_vec(const float* __restrict__ in, unsigned short* __restrict__ out,
                                long long total)
{
    long long i = ((long long)blockIdx.x * blockDim.x + threadIdx.x) * 4;
    if (i + 4 <= total) {
        float4 v = *(const float4*)(in + i);
        ushort4 o;
        o.x = f2bf(v.x); o.y = f2bf(v.y); o.z = f2bf(v.z); o.w = f2bf(v.w);
        *(ushort4*)(out + i) = o;
    } else {
        for (; i < total; i++) out[i] = f2bf(in[i]);
    }
}

// W [K,N] fp32 -> Wt [N,K] bf16
__global__ void transpose_bf16(const float* __restrict__ W, unsigned short* __restrict__ Wt,
                               int K, int N)
{
    int t = blockIdx.x * blockDim.x + threadIdx.x;
    if (t >= K * N) return;
    int k = t / N, nn = t - k * N;
    Wt[(size_t)nn * K + k] = f2bf(W[t]);
}

// ---------------- bf16 MFMA GEMM: C[M,N] = A[M,K] @ Bt[N,K]^T + bias ----------------
// 64x64 tile, 4 waves (2x2), each wave 32x32 via 2x2 16x16x32 fragments.
__global__ __launch_bounds__(256) void gemm_mfma(
    const unsigned short* __restrict__ A,   // [M,K] bf16
    const unsigned short* __restrict__ Bt,  // [N,K] bf16
    const float* __restrict__ bias, float* __restrict__ C,
    int M, int N, int K)
{
    int wid = threadIdx.x >> 6;
    int lane = threadIdx.x & 63;
    int wm = wid >> 1, wn = wid & 1;
    int bm = blockIdx.x * 64, bn = blockIdx.y * 64;
    int r16 = lane & 15, kg = lane >> 4;
    f32x4 acc[2][2] = {};
    const int rowA0 = bm + wm * 32 + r16;
    const int rowB0 = bn + wn * 32 + r16;
    for (int k0 = 0; k0 < K; k0 += 32) {
        int kofs = k0 + kg * 8;
        bf16x8 a[2], b[2];
#pragma unroll
        for (int f = 0; f < 2; f++) {
            int ra = rowA0 + 16 * f;
            ra = (ra < M) ? ra : 0;
            a[f] = *(const bf16x8*)(A + (size_t)ra * K + kofs);
            b[f] = *(const bf16x8*)(Bt + (size_t)(rowB0 + 16 * f) * K + kofs);
        }
#pragma unroll
        for (int i = 0; i < 2; i++)
#pragma unroll
            for (int j = 0; j < 2; j++)
                acc[i][j] = __builtin_amdgcn_mfma_f32_16x16x32_bf16(a[i], b[j], acc[i][j], 0, 0, 0);
    }
    int crow = (lane >> 4) * 4;
    int ccol = lane & 15;
#pragma unroll
    for (int i = 0; i < 2; i++) {
#pragma unroll
        for (int j = 0; j < 2; j++) {
            int col = bn + wn * 32 + j * 16 + ccol;
            float bv = bias[col];
#pragma unroll
            for (int r = 0; r < 4; r++) {
                int row = bm + wm * 32 + i * 16 + crow + r;
                if (row < M) C[(size_t)row * N + col] = acc[i][j][r] + bv;
            }
        }
    }
}

// ---------------- CSR build ----------------
__global__ void hist_dst(const int* __restrict__ eidx, const int* __restrict__ flagp,
                         int E, int n, int* __restrict__ cnt)
{
    int t = blockIdx.x * blockDim.x + threadIdx.x;
    if (t >= E + n) return;
    int is64 = *flagp;
    int d = (t < E) ? ld_idx(eidx, E + t, is64) : (t - E);
    atomicAdd(&cnt[d], 1);
}

__global__ __launch_bounds__(1024) void scan_excl(const int* __restrict__ cnt,
                                                  int* __restrict__ rowptr, int n)
{
    __shared__ int buf[1024];
    __shared__ int carry_s;
    int tid = threadIdx.x;
    if (tid == 0) carry_s = 0;
    __syncthreads();
    for (int base = 0; base < n; base += 1024) {
        int i = base + tid;
        int v = (i < n) ? cnt[i] : 0;
        buf[tid] = v;
        __syncthreads();
        int acc = v;
        for (int off = 1; off < 1024; off <<= 1) {
            int t = (tid >= off) ? buf[tid - off] : 0;
            __syncthreads();
            acc += t;
            buf[tid] = acc;
            __syncthreads();
        }
        int carry = carry_s;
        if (i < n) rowptr[i] = carry + acc - v;
        __syncthreads();
        if (tid == 1023) carry_s = carry + acc;
        __syncthreads();
    }
    if (tid == 0) rowptr[n] = carry_s;
}

// emits sord (src node per CSR slot) and pos_edge (edge id -> CSR slot)
__global__ void scatter_edges(const int* __restrict__ eidx, const int* __restrict__ flagp,
                              int E, int n, const int* __restrict__ rowptr,
                              int* __restrict__ cursor, int* __restrict__ sord,
                              int* __restrict__ pos_edge)
{
    int t = blockIdx.x * blockDim.x + threadIdx.x;
    if (t >= E + n) return;
    int is64 = *flagp;
    int s, d;
    if (t < E) { s = ld_idx(eidx, t, is64); d = ld_idx(eidx, E + t, is64); }
    else { s = t - E; d = s; }
    int pos = atomicAdd(&cursor[d], 1);
    int slot = rowptr[d] + pos;
    sord[slot] = s;
    pos_edge[t] = slot;
}

// ---------------- dense score kernels (write into CSR order) ----------------
// H=4: one wave per edge, all 4 heads. lane: h = lane>>4, c0 = (lane&15)*4.
__global__ __launch_bounds__(256) void edge_score4(
    const float* __restrict__ xl, const float* __restrict__ xr,
    const float* __restrict__ att, const int* __restrict__ eidx,
    const int* __restrict__ flagp, const int* __restrict__ pos_edge,
    int E, int n, float* __restrict__ score_csr /* [4][Etot] */)
{
    int gw = (blockIdx.x * blockDim.x + threadIdx.x) >> 6;
    int lane = threadIdx.x & 63;
    int Etot = E + n;
    if (gw >= Etot) return;
    int is64 = *flagp;
    int s, d;
    if (gw < E) { s = ld_idx(eidx, gw, is64); d = ld_idx(eidx, E + gw, is64); }
    else { s = gw - E; d = s; }
    float4 xlv = *(const float4*)(xl + (size_t)s * 256 + lane * 4);
    float4 xrv = *(const float4*)(xr + (size_t)d * 256 + lane * 4);
    float4 av  = *(const float4*)(att + lane * 4);
    float p = lrelu(xlv.x + xrv.x, 0.2f) * av.x;
    p = fmaf(lrelu(xlv.y + xrv.y, 0.2f), av.y, p);
    p = fmaf(lrelu(xlv.z + xrv.z, 0.2f), av.z, p);
    p = fmaf(lrelu(xlv.w + xrv.w, 0.2f), av.w, p);
    p += __shfl_xor(p, 1);
    p += __shfl_xor(p, 2);
    p += __shfl_xor(p, 4);
    p += __shfl_xor(p, 8);
    if ((lane & 15) == 0) {
        int h = lane >> 4;
        score_csr[(size_t)h * Etot + pos_edge[gw]] = p;
    }
}

// H=1: 4 edges per wave (16 lanes each).
__global__ __launch_bounds__(256) void edge_score1(
    const float* __restrict__ xl, const float* __restrict__ xr,
    const float* __restrict__ att, const int* __restrict__ eidx,
    const int* __restrict__ flagp, const int* __restrict__ pos_edge,
    int E, int n, float* __restrict__ score_csr)
{
    int gw = (blockIdx.x * blockDim.x + threadIdx.x) >> 6;
    int lane = threadIdx.x & 63;
    int Etot = E + n;
    int e = gw * 4 + (lane >> 4);
    int valid = e < Etot;
    int ec = valid ? e : 0;
    int is64 = *flagp;
    int s, d;
    if (ec < E) { s = ld_idx(eidx, ec, is64); d = ld_idx(eidx, E + ec, is64); }
    else { s = ec - E; d = s; }
    int c0 = (lane & 15) * 4;
    float4 xlv = *(const float4*)(xl + (size_t)s * 64 + c0);
    float4 xrv = *(const float4*)(xr + (size_t)d * 64 + c0);
    float4 av  = *(const float4*)(att + c0);
    float p = lrelu(xlv.x + xrv.x, 0.2f) * av.x;
    p = fmaf(lrelu(xlv.y + xrv.y, 0.2f), av.y, p);
    p = fmaf(lrelu(xlv.z + xrv.z, 0.2f), av.z, p);
    p = fmaf(lrelu(xlv.w + xrv.w, 0.2f), av.w, p);
    p += __shfl_xor(p, 1);
    p += __shfl_xor(p, 2);
    p += __shfl_xor(p, 4);
    p += __shfl_xor(p, 8);
    if (valid && (lane & 15) == 0) score_csr[pos_edge[ec]] = p;
}

// ---------------- aggregation: one wave per (node, head), online softmax ----------------
#define ONLINE(v, xv) { float nm = fmaxf(m, (v)); float sc_ = __expf(m - nm); \
                        float ev = __expf((v) - nm); ssum = ssum * sc_ + ev; \
                        o = o * sc_ + ev * (xv); m = nm; }

template <int H, bool BF16OUT>
__global__ __launch_bounds__(256) void node_aggr(
    const float* __restrict__ xl, const float* __restrict__ bias,
    const int* __restrict__ rowptr, const int* __restrict__ sord,
    const float* __restrict__ score_csr, int Etot, int n,
    float* __restrict__ outf, unsigned short* __restrict__ outb,
    int do_lrelu, float slope)
{
    int gw = (blockIdx.x * blockDim.x + threadIdx.x) >> 6;
    int lane = threadIdx.x & 63;
    if (gw >= n * H) return;
    int d = gw / H, h = gw - d * H;
    int beg = rowptr[d], end = rowptr[d + 1];
    const float* scb = score_csr + (size_t)h * Etot;
    const float* xlb = xl + h * 64 + lane;
    float m = -1e30f, ssum = 0.f, o = 0.f;
    int i = beg;
    for (; i + 4 <= end; i += 4) {
        int s0 = sord[i], s1 = sord[i + 1], s2 = sord[i + 2], s3 = sord[i + 3];
        float v0 = scb[i], v1 = scb[i + 1], v2 = scb[i + 2], v3 = scb[i + 3];
        float x0 = xlb[(size_t)s0 * (H * 64)];
        float x1 = xlb[(size_t)s1 * (H * 64)];
        float x2 = xlb[(size_t)s2 * (H * 64)];
        float x3 = xlb[(size_t)s3 * (H * 64)];
        ONLINE(v0, x0); ONLINE(v1, x1); ONLINE(v2, x2); ONLINE(v3, x3);
    }
    for (; i < end; i++) {
        int s0 = sord[i];
        float v0 = scb[i];
        float x0 = xlb[(size_t)s0 * (H * 64)];
        ONLINE(v0, x0);
    }
    float res = o / (ssum + 1e-16f) + bias[h * 64 + lane];
    if (do_lrelu) res = lrelu(res, slope);
    size_t oi = (size_t)d * (H * 64) + h * 64 + lane;
    if (BF16OUT) outb[oi] = f2bf(res);
    else outf[oi] = res;
}

// fused predict head
__global__ void predict_head(const float* __restrict__ h2,
                             const float* __restrict__ Wp1, const float* __restrict__ bp1,
                             const float* __restrict__ Wp2, const float* __restrict__ bp2,
                             float* __restrict__ logits, int n)
{
    int i = blockIdx.x * blockDim.x + threadIdx.x;
    if (i >= n) return;
    float h[64];
#pragma unroll
    for (int c = 0; c < 64; c++) h[c] = h2[(long long)i * 64 + c];
    float logit = bp2[0];
#pragma unroll
    for (int j = 0; j < 32; j++) {
        float z = bp1[j];
#pragma unroll
        for (int c = 0; c < 64; c++) z += h[c] * Wp1[c * 32 + j];
        z = lrelu(z, 0.01f);
        logit += z * Wp2[j];
    }
    logits[i] = logit;
}

extern "C" void kernel_launch(void* const* d_in, const int* in_sizes, int n_in,
                              void* d_out, int out_size, void* d_ws, size_t ws_size,
                              hipStream_t stream)
{
    const float* x    = (const float*)d_in[0];
    const int*   eidx = (const int*)d_in[1];
    const float* W1l  = (const float*)d_in[2];
    const float* b1l  = (const float*)d_in[3];
    const float* W1r  = (const float*)d_in[4];
    const float* b1r  = (const float*)d_in[5];
    const float* att1 = (const float*)d_in[6];
    const float* bias1= (const float*)d_in[7];
    const float* W2l  = (const float*)d_in[8];
    const float* b2l  = (const float*)d_in[9];
    const float* W2r  = (const float*)d_in[10];
    const float* b2r  = (const float*)d_in[11];
    const float* att2 = (const float*)d_in[12];
    const float* bias2= (const float*)d_in[13];
    const float* Wp1  = (const float*)d_in[14];
    const float* bp1  = (const float*)d_in[15];
    const float* Wp2  = (const float*)d_in[16];
    const float* bp2  = (const float*)d_in[17];

    const int n = in_sizes[0] / 256;  // 50000
    const int E = in_sizes[1] / 2;    // 600000
    const int Etot = E + n;

    float* out = (float*)d_out;       // [0,n): logits ; [n, n+n*64): h
    float* ws  = (float*)d_ws;

    // workspace layout
    float*          xl1   = ws;                                        // n*256 f32
    float*          xr1   = xl1 + (size_t)n * 256;                     // n*256 f32
    unsigned short* xb    = (unsigned short*)(xr1 + (size_t)n * 256);  // n*256 bf16 (reused as h1b)
    float*          score = (float*)(xb + (size_t)n * 256);            // 4*Etot f32
    unsigned short* w1lt  = (unsigned short*)(score + (size_t)4 * Etot); // 256*256
    unsigned short* w1rt  = w1lt + 65536;
    unsigned short* w2lt  = w1rt + 65536;                              // 64*256
    unsigned short* w2rt  = w2lt + 16384;
    int*            rowptr= (int*)(w2rt + 16384);                      // n+1
    int*            cnt   = rowptr + (n + 1);                          // n
    int*            sord  = cnt + n;                                   // Etot
    int*            pos_e = sord + Etot;                               // Etot
    int*            flagp = pos_e + Etot;
    float*          xl2   = xl1;                                       // n*64 (reuse)
    float*          xr2   = xl1 + (size_t)n * 64;
    unsigned short* h1b   = xb;                                        // reuse after gemm1
    float*          h2    = out + n;

    detect_i64<<<1, 64, 0, stream>>>((const unsigned int*)eidx, flagp);

    // ---- CSR build ----
    hipMemsetAsync(cnt, 0, (size_t)n * sizeof(int), stream);
    hist_dst<<<(Etot + 255) / 256, 256, 0, stream>>>(eidx, flagp, E, n, cnt);
    scan_excl<<<1, 1024, 0, stream>>>(cnt, rowptr, n);
    hipMemsetAsync(cnt, 0, (size_t)n * sizeof(int), stream);
    scatter_edges<<<(Etot + 255) / 256, 256, 0, stream>>>(eidx, flagp, E, n, rowptr, cnt, sord, pos_e);

    // ---- conversions ----
    {
        long long tot = (long long)n * 256;
        f32_to_bf16_vec<<<(int)((tot / 4 + 255) / 256), 256, 0, stream>>>(x, xb, tot);
        transpose_bf16<<<(256 * 256 + 255) / 256, 256, 0, stream>>>(W1l, w1lt, 256, 256);
        transpose_bf16<<<(256 * 256 + 255) / 256, 256, 0, stream>>>(W1r, w1rt, 256, 256);
        transpose_bf16<<<(256 * 64 + 255) / 256, 256, 0, stream>>>(W2l, w2lt, 256, 64);
        transpose_bf16<<<(256 * 64 + 255) / 256, 256, 0, stream>>>(W2r, w2rt, 256, 64);
    }

    // ---- layer 1 projections (bf16 MFMA) ----
    {
        dim3 grid((n + 63) / 64, 4);
        gemm_mfma<<<grid, 256, 0, stream>>>(xb, w1lt, b1l, xl1, n, 256, 256);
        gemm_mfma<<<grid, 256, 0, stream>>>(xb, w1rt, b1r, xr1, n, 256, 256);
    }

    // ---- layer 1 edge phase ----
    edge_score4<<<(Etot + 3) / 4, 256, 0, stream>>>(xl1, xr1, att1, eidx, flagp, pos_e, E, n, score);
    node_aggr<4, true><<<(n * 4 + 3) / 4, 256, 0, stream>>>(
        xl1, bias1, rowptr, sord, score, Etot, n, nullptr, h1b, 1, 0.01f);

    // ---- layer 2 projections ----
    {
        dim3 grid((n + 63) / 64, 1);
        gemm_mfma<<<grid, 256, 0, stream>>>(h1b, w2lt, b2l, xl2, n, 64, 256);
        gemm_mfma<<<grid, 256, 0, stream>>>(h1b, w2rt, b2r, xr2, n, 64, 256);
    }

    // ---- layer 2 edge phase ----
    edge_score1<<<(Etot + 15) / 16, 256, 0, stream>>>(xl2, xr2, att2, eidx, flagp, pos_e, E, n, score);
    node_aggr<1, false><<<(n + 3) / 4, 256, 0, stream>>>(
        xl2, bias2, rowptr, sord, score, Etot, n, h2, nullptr, 0, 0.f);

    // ---- predict head ----
    predict_head<<<(n + 255) / 256, 256, 0, stream>>>(h2, Wp1, bp1, Wp2, bp2, out, n);
}

// Round 4
// 567.455 us; speedup vs baseline: 3.2161x; 1.3329x over previous
//
#include <hip/hip_runtime.h>

typedef __attribute__((ext_vector_type(8))) __bf16 bf16x8;
typedef __attribute__((ext_vector_type(4))) float f32x4;

__device__ __forceinline__ float lrelu(float v, float s) { return v > 0.f ? v : v * s; }

__device__ __forceinline__ unsigned short f2bf(float f) {
    unsigned int u = __float_as_uint(f);
    u += 0x7FFFu + ((u >> 16) & 1u);
    return (unsigned short)(u >> 16);
}

// edge index load that handles int32 or int64 storage (flag from detect kernel)
__device__ __forceinline__ int ld_idx(const int* p, int e, int is64) {
    return is64 ? (int)(((const long long*)p)[e]) : p[e];
}

__global__ void detect_i64(const unsigned int* idx, int* flag) {
    if (blockIdx.x == 0 && threadIdx.x == 0) {
        int all0 = 1;
        for (int i = 1; i < 256; i += 2) {
            if (idx[i] != 0u) { all0 = 0; break; }
        }
        *flag = all0;
    }
}

// ---------------- conversion kernels ----------------
__global__ void f32_to_bf16_vec(const float* __restrict__ in, unsigned short* __restrict__ out,
                                long long total)
{
    long long i = ((long long)blockIdx.x * blockDim.x + threadIdx.x) * 4;
    if (i + 4 <= total) {
        float4 v = *(const float4*)(in + i);
        ushort4 o;
        o.x = f2bf(v.x); o.y = f2bf(v.y); o.z = f2bf(v.z); o.w = f2bf(v.w);
        *(ushort4*)(out + i) = o;
    } else {
        for (; i < total; i++) out[i] = f2bf(in[i]);
    }
}

// W [K,N] fp32 -> Wt [N,K] bf16
__global__ void transpose_bf16(const float* __restrict__ W, unsigned short* __restrict__ Wt,
                               int K, int N)
{
    int t = blockIdx.x * blockDim.x + threadIdx.x;
    if (t >= K * N) return;
    int k = t / N, nn = t - k * N;
    Wt[(size_t)nn * K + k] = f2bf(W[t]);
}

// ---------------- bf16 MFMA GEMM: C[M,N] = A[M,K] @ Bt[N,K]^T + bias ----------------
// 64x64 tile, 4 waves (2x2), each wave 32x32 via 2x2 16x16x32 fragments.
__global__ __launch_bounds__(256) void gemm_mfma(
    const unsigned short* __restrict__ A,   // [M,K] bf16
    const unsigned short* __restrict__ Bt,  // [N,K] bf16
    const float* __restrict__ bias, float* __restrict__ C,
    int M, int N, int K)
{
    int wid = threadIdx.x >> 6;
    int lane = threadIdx.x & 63;
    int wm = wid >> 1, wn = wid & 1;
    int bm = blockIdx.x * 64, bn = blockIdx.y * 64;
    int r16 = lane & 15, kg = lane >> 4;
    f32x4 acc[2][2] = {};
    const int rowA0 = bm + wm * 32 + r16;
    const int rowB0 = bn + wn * 32 + r16;
    for (int k0 = 0; k0 < K; k0 += 32) {
        int kofs = k0 + kg * 8;
        bf16x8 a[2], b[2];
#pragma unroll
        for (int f = 0; f < 2; f++) {
            int ra = rowA0 + 16 * f;
            ra = (ra < M) ? ra : 0;
            a[f] = *(const bf16x8*)(A + (size_t)ra * K + kofs);
            b[f] = *(const bf16x8*)(Bt + (size_t)(rowB0 + 16 * f) * K + kofs);
        }
#pragma unroll
        for (int i = 0; i < 2; i++)
#pragma unroll
            for (int j = 0; j < 2; j++)
                acc[i][j] = __builtin_amdgcn_mfma_f32_16x16x32_bf16(a[i], b[j], acc[i][j], 0, 0, 0);
    }
    int crow = (lane >> 4) * 4;
    int ccol = lane & 15;
#pragma unroll
    for (int i = 0; i < 2; i++) {
#pragma unroll
        for (int j = 0; j < 2; j++) {
            int col = bn + wn * 32 + j * 16 + ccol;
            float bv = bias[col];
#pragma unroll
            for (int r = 0; r < 4; r++) {
                int row = bm + wm * 32 + i * 16 + crow + r;
                if (row < M) C[(size_t)row * N + col] = acc[i][j][r] + bv;
            }
        }
    }
}

// ---------------- CSR build ----------------
__global__ void hist_dst(const int* __restrict__ eidx, const int* __restrict__ flagp,
                         int E, int n, int* __restrict__ cnt)
{
    int t = blockIdx.x * blockDim.x + threadIdx.x;
    if (t >= E + n) return;
    int is64 = *flagp;
    int d = (t < E) ? ld_idx(eidx, E + t, is64) : (t - E);
    atomicAdd(&cnt[d], 1);
}

__global__ __launch_bounds__(1024) void scan_excl(const int* __restrict__ cnt,
                                                  int* __restrict__ rowptr, int n)
{
    __shared__ int buf[1024];
    __shared__ int carry_s;
    int tid = threadIdx.x;
    if (tid == 0) carry_s = 0;
    __syncthreads();
    for (int base = 0; base < n; base += 1024) {
        int i = base + tid;
        int v = (i < n) ? cnt[i] : 0;
        buf[tid] = v;
        __syncthreads();
        int acc = v;
        for (int off = 1; off < 1024; off <<= 1) {
            int t = (tid >= off) ? buf[tid - off] : 0;
            __syncthreads();
            acc += t;
            buf[tid] = acc;
            __syncthreads();
        }
        int carry = carry_s;
        if (i < n) rowptr[i] = carry + acc - v;
        __syncthreads();
        if (tid == 1023) carry_s = carry + acc;
        __syncthreads();
    }
    if (tid == 0) rowptr[n] = carry_s;
}

// emits sord (src node per CSR slot)
__global__ void scatter_edges(const int* __restrict__ eidx, const int* __restrict__ flagp,
                              int E, int n, const int* __restrict__ rowptr,
                              int* __restrict__ cursor, int* __restrict__ sord)
{
    int t = blockIdx.x * blockDim.x + threadIdx.x;
    if (t >= E + n) return;
    int is64 = *flagp;
    int s, d;
    if (t < E) { s = ld_idx(eidx, t, is64); d = ld_idx(eidx, E + t, is64); }
    else { s = t - E; d = s; }
    int pos = atomicAdd(&cursor[d], 1);
    sord[rowptr[d] + pos] = s;
}

// ---------------- fused edge phase: one wave per (node, head) ----------------
// Per edge: gather xl[s,h,:] ONCE; use for both score (64-lane butterfly) and
// weighted accumulation (online softmax). CSR-ordered, unroll-4 for ILP.
#define ONLINE(v, xv) { float nm = fmaxf(m, (v)); float sc_ = __expf(m - nm); \
                        float ev = __expf((v) - nm); ssum = ssum * sc_ + ev; \
                        o = o * sc_ + ev * (xv); m = nm; }

#define BFLY(v) { v += __shfl_xor(v, 1); v += __shfl_xor(v, 2); v += __shfl_xor(v, 4); \
                  v += __shfl_xor(v, 8); v += __shfl_xor(v, 16); v += __shfl_xor(v, 32); }

template <int H, bool BF16OUT>
__global__ __launch_bounds__(256) void node_attn2(
    const float* __restrict__ xl, const float* __restrict__ xr,
    const float* __restrict__ att, const float* __restrict__ bias,
    const int* __restrict__ rowptr, const int* __restrict__ sord, int n,
    float* __restrict__ outf, unsigned short* __restrict__ outb,
    int do_lrelu, float slope)
{
    int gw = (blockIdx.x * blockDim.x + threadIdx.x) >> 6;
    int lane = threadIdx.x & 63;
    if (gw >= n * H) return;
    int d = gw / H, h = gw - d * H;
    int beg = rowptr[d], end = rowptr[d + 1];
    float xrv = xr[(size_t)d * (H * 64) + h * 64 + lane];
    float attv = att[h * 64 + lane];
    const float* xlb = xl + h * 64 + lane;
    float m = -1e30f, ssum = 0.f, o = 0.f;
    int i = beg;
    for (; i + 4 <= end; i += 4) {
        int s0 = sord[i], s1 = sord[i + 1], s2 = sord[i + 2], s3 = sord[i + 3];
        float x0 = xlb[(size_t)s0 * (H * 64)];
        float x1 = xlb[(size_t)s1 * (H * 64)];
        float x2 = xlb[(size_t)s2 * (H * 64)];
        float x3 = xlb[(size_t)s3 * (H * 64)];
        float v0 = lrelu(x0 + xrv, 0.2f) * attv;
        float v1 = lrelu(x1 + xrv, 0.2f) * attv;
        float v2 = lrelu(x2 + xrv, 0.2f) * attv;
        float v3 = lrelu(x3 + xrv, 0.2f) * attv;
        BFLY(v0); BFLY(v1); BFLY(v2); BFLY(v3);
        ONLINE(v0, x0); ONLINE(v1, x1); ONLINE(v2, x2); ONLINE(v3, x3);
    }
    for (; i < end; i++) {
        int s0 = sord[i];
        float x0 = xlb[(size_t)s0 * (H * 64)];
        float v0 = lrelu(x0 + xrv, 0.2f) * attv;
        BFLY(v0);
        ONLINE(v0, x0);
    }
    float res = o / (ssum + 1e-16f) + bias[h * 64 + lane];
    if (do_lrelu) res = lrelu(res, slope);
    size_t oi = (size_t)d * (H * 64) + h * 64 + lane;
    if (BF16OUT) outb[oi] = f2bf(res);
    else outf[oi] = res;
}

// fused predict head
__global__ void predict_head(const float* __restrict__ h2,
                             const float* __restrict__ Wp1, const float* __restrict__ bp1,
                             const float* __restrict__ Wp2, const float* __restrict__ bp2,
                             float* __restrict__ logits, int n)
{
    int i = blockIdx.x * blockDim.x + threadIdx.x;
    if (i >= n) return;
    float h[64];
#pragma unroll
    for (int c = 0; c < 64; c++) h[c] = h2[(long long)i * 64 + c];
    float logit = bp2[0];
#pragma unroll
    for (int j = 0; j < 32; j++) {
        float z = bp1[j];
#pragma unroll
        for (int c = 0; c < 64; c++) z += h[c] * Wp1[c * 32 + j];
        z = lrelu(z, 0.01f);
        logit += z * Wp2[j];
    }
    logits[i] = logit;
}

extern "C" void kernel_launch(void* const* d_in, const int* in_sizes, int n_in,
                              void* d_out, int out_size, void* d_ws, size_t ws_size,
                              hipStream_t stream)
{
    const float* x    = (const float*)d_in[0];
    const int*   eidx = (const int*)d_in[1];
    const float* W1l  = (const float*)d_in[2];
    const float* b1l  = (const float*)d_in[3];
    const float* W1r  = (const float*)d_in[4];
    const float* b1r  = (const float*)d_in[5];
    const float* att1 = (const float*)d_in[6];
    const float* bias1= (const float*)d_in[7];
    const float* W2l  = (const float*)d_in[8];
    const float* b2l  = (const float*)d_in[9];
    const float* W2r  = (const float*)d_in[10];
    const float* b2r  = (const float*)d_in[11];
    const float* att2 = (const float*)d_in[12];
    const float* bias2= (const float*)d_in[13];
    const float* Wp1  = (const float*)d_in[14];
    const float* bp1  = (const float*)d_in[15];
    const float* Wp2  = (const float*)d_in[16];
    const float* bp2  = (const float*)d_in[17];

    const int n = in_sizes[0] / 256;  // 50000
    const int E = in_sizes[1] / 2;    // 600000
    const int Etot = E + n;

    float* out = (float*)d_out;       // [0,n): logits ; [n, n+n*64): h
    float* ws  = (float*)d_ws;

    // workspace layout
    float*          xl1   = ws;                                        // n*256 f32
    float*          xr1   = xl1 + (size_t)n * 256;                     // n*256 f32
    unsigned short* xb    = (unsigned short*)(xr1 + (size_t)n * 256);  // n*256 bf16 (reused as h1b)
    unsigned short* w1lt  = xb + (size_t)n * 256;                      // 256*256
    unsigned short* w1rt  = w1lt + 65536;
    unsigned short* w2lt  = w1rt + 65536;                              // 64*256
    unsigned short* w2rt  = w2lt + 16384;
    int*            rowptr= (int*)(w2rt + 16384);                      // n+1
    int*            cnt   = rowptr + (n + 1);                          // n
    int*            sord  = cnt + n;                                   // Etot
    int*            flagp = sord + Etot;
    float*          xl2   = xl1;                                       // n*64 (reuse)
    float*          xr2   = xl1 + (size_t)n * 64;
    unsigned short* h1b   = xb;                                        // reuse after gemm1
    float*          h2    = out + n;

    detect_i64<<<1, 64, 0, stream>>>((const unsigned int*)eidx, flagp);

    // ---- CSR build ----
    hipMemsetAsync(cnt, 0, (size_t)n * sizeof(int), stream);
    hist_dst<<<(Etot + 255) / 256, 256, 0, stream>>>(eidx, flagp, E, n, cnt);
    scan_excl<<<1, 1024, 0, stream>>>(cnt, rowptr, n);
    hipMemsetAsync(cnt, 0, (size_t)n * sizeof(int), stream);
    scatter_edges<<<(Etot + 255) / 256, 256, 0, stream>>>(eidx, flagp, E, n, rowptr, cnt, sord);

    // ---- conversions ----
    {
        long long tot = (long long)n * 256;
        f32_to_bf16_vec<<<(int)((tot / 4 + 255) / 256), 256, 0, stream>>>(x, xb, tot);
        transpose_bf16<<<(256 * 256 + 255) / 256, 256, 0, stream>>>(W1l, w1lt, 256, 256);
        transpose_bf16<<<(256 * 256 + 255) / 256, 256, 0, stream>>>(W1r, w1rt, 256, 256);
        transpose_bf16<<<(256 * 64 + 255) / 256, 256, 0, stream>>>(W2l, w2lt, 256, 64);
        transpose_bf16<<<(256 * 64 + 255) / 256, 256, 0, stream>>>(W2r, w2rt, 256, 64);
    }

    // ---- layer 1 projections (bf16 MFMA) ----
    {
        dim3 grid((n + 63) / 64, 4);
        gemm_mfma<<<grid, 256, 0, stream>>>(xb, w1lt, b1l, xl1, n, 256, 256);
        gemm_mfma<<<grid, 256, 0, stream>>>(xb, w1rt, b1r, xr1, n, 256, 256);
    }

    // ---- layer 1 edge phase (fused score+aggregate, bias + leaky 0.01) ----
    node_attn2<4, true><<<(n * 4 + 3) / 4, 256, 0, stream>>>(
        xl1, xr1, att1, bias1, rowptr, sord, n, nullptr, h1b, 1, 0.01f);

    // ---- layer 2 projections ----
    {
        dim3 grid((n + 63) / 64, 1);
        gemm_mfma<<<grid, 256, 0, stream>>>(h1b, w2lt, b2l, xl2, n, 64, 256);
        gemm_mfma<<<grid, 256, 0, stream>>>(h1b, w2rt, b2r, xr2, n, 64, 256);
    }

    // ---- layer 2 edge phase ----
    node_attn2<1, false><<<(n + 3) / 4, 256, 0, stream>>>(
        xl2, xr2, att2, bias2, rowptr, sord, n, h2, nullptr, 0, 0.f);

    // ---- predict head ----
    predict_head<<<(n + 255) / 256, 256, 0, stream>>>(h2, Wp1, bp1, Wp2, bp2, out, n);
}

// Round 6
// 466.985 us; speedup vs baseline: 3.9080x; 1.2151x over previous
//
#include <hip/hip_runtime.h>

typedef __attribute__((ext_vector_type(8))) __bf16 bf16x8;
typedef __attribute__((ext_vector_type(4))) float f32x4;

#define EXP2 __builtin_amdgcn_exp2f
#define LOG2E 1.44269504f

__device__ __forceinline__ float lrelu(float v, float s) { return v > 0.f ? v : v * s; }

__device__ __forceinline__ unsigned short f2bf(float f) {
    unsigned int u = __float_as_uint(f);
    u += 0x7FFFu + ((u >> 16) & 1u);
    return (unsigned short)(u >> 16);
}

// edge index load that handles int32 or int64 storage (flag from detect kernel)
__device__ __forceinline__ int ld_idx(const int* p, int e, int is64) {
    return is64 ? (int)(((const long long*)p)[e]) : p[e];
}

__global__ void detect_i64(const unsigned int* idx, int* flag) {
    if (blockIdx.x == 0 && threadIdx.x == 0) {
        int all0 = 1;
        for (int i = 1; i < 256; i += 2) {
            if (idx[i] != 0u) { all0 = 0; break; }
        }
        *flag = all0;
    }
}

// ---------------- conversion kernels ----------------
__global__ void f32_to_bf16_vec(const float* __restrict__ in, unsigned short* __restrict__ out,
                                long long total)
{
    long long i = ((long long)blockIdx.x * blockDim.x + threadIdx.x) * 4;
    if (i + 4 <= total) {
        float4 v = *(const float4*)(in + i);
        ushort4 o;
        o.x = f2bf(v.x); o.y = f2bf(v.y); o.z = f2bf(v.z); o.w = f2bf(v.w);
        *(ushort4*)(out + i) = o;
    } else {
        for (; i < total; i++) out[i] = f2bf(in[i]);
    }
}

// W [K,N] fp32 -> Wt [N,K] bf16
__global__ void transpose_bf16(const float* __restrict__ W, unsigned short* __restrict__ Wt,
                               int K, int N)
{
    int t = blockIdx.x * blockDim.x + threadIdx.x;
    if (t >= K * N) return;
    int k = t / N, nn = t - k * N;
    Wt[(size_t)nn * K + k] = f2bf(W[t]);
}

// ---------------- bf16 MFMA GEMM: C[M,N] = A[M,K] @ Bt[N,K]^T + bias ----------------
__global__ __launch_bounds__(256) void gemm_mfma(
    const unsigned short* __restrict__ A,   // [M,K] bf16
    const unsigned short* __restrict__ Bt,  // [N,K] bf16
    const float* __restrict__ bias, float* __restrict__ C,
    int M, int N, int K)
{
    int wid = threadIdx.x >> 6;
    int lane = threadIdx.x & 63;
    int wm = wid >> 1, wn = wid & 1;
    int bm = blockIdx.x * 64, bn = blockIdx.y * 64;
    int r16 = lane & 15, kg = lane >> 4;
    f32x4 acc[2][2] = {};
    const int rowA0 = bm + wm * 32 + r16;
    const int rowB0 = bn + wn * 32 + r16;
    for (int k0 = 0; k0 < K; k0 += 32) {
        int kofs = k0 + kg * 8;
        bf16x8 a[2], b[2];
#pragma unroll
        for (int f = 0; f < 2; f++) {
            int ra = rowA0 + 16 * f;
            ra = (ra < M) ? ra : 0;
            a[f] = *(const bf16x8*)(A + (size_t)ra * K + kofs);
            b[f] = *(const bf16x8*)(Bt + (size_t)(rowB0 + 16 * f) * K + kofs);
        }
#pragma unroll
        for (int i = 0; i < 2; i++)
#pragma unroll
            for (int j = 0; j < 2; j++)
                acc[i][j] = __builtin_amdgcn_mfma_f32_16x16x32_bf16(a[i], b[j], acc[i][j], 0, 0, 0);
    }
    int crow = (lane >> 4) * 4;
    int ccol = lane & 15;
#pragma unroll
    for (int i = 0; i < 2; i++) {
#pragma unroll
        for (int j = 0; j < 2; j++) {
            int col = bn + wn * 32 + j * 16 + ccol;
            float bv = bias[col];
#pragma unroll
            for (int r = 0; r < 4; r++) {
                int row = bm + wm * 32 + i * 16 + crow + r;
                if (row < M) C[(size_t)row * N + col] = acc[i][j][r] + bv;
            }
        }
    }
}

// ---------------- CSR build ----------------
__global__ void hist_dst(const int* __restrict__ eidx, const int* __restrict__ flagp,
                         int E, int n, int* __restrict__ cnt)
{
    int t = blockIdx.x * blockDim.x + threadIdx.x;
    if (t >= E + n) return;
    int is64 = *flagp;
    int d = (t < E) ? ld_idx(eidx, E + t, is64) : (t - E);
    atomicAdd(&cnt[d], 1);
}

__global__ __launch_bounds__(1024) void scan_excl(const int* __restrict__ cnt,
                                                  int* __restrict__ rowptr, int n)
{
    __shared__ int buf[1024];
    __shared__ int carry_s;
    int tid = threadIdx.x;
    if (tid == 0) carry_s = 0;
    __syncthreads();
    for (int base = 0; base < n; base += 1024) {
        int i = base + tid;
        int v = (i < n) ? cnt[i] : 0;
        buf[tid] = v;
        __syncthreads();
        int acc = v;
        for (int off = 1; off < 1024; off <<= 1) {
            int t = (tid >= off) ? buf[tid - off] : 0;
            __syncthreads();
            acc += t;
            buf[tid] = acc;
            __syncthreads();
        }
        int carry = carry_s;
        if (i < n) rowptr[i] = carry + acc - v;
        __syncthreads();
        if (tid == 1023) carry_s = carry + acc;
        __syncthreads();
    }
    if (tid == 0) rowptr[n] = carry_s;
}

// emits sord (src node per CSR slot)
__global__ void scatter_edges(const int* __restrict__ eidx, const int* __restrict__ flagp,
                              int E, int n, const int* __restrict__ rowptr,
                              int* __restrict__ cursor, int* __restrict__ sord)
{
    int t = blockIdx.x * blockDim.x + threadIdx.x;
    if (t >= E + n) return;
    int is64 = *flagp;
    int s, d;
    if (t < E) { s = ld_idx(eidx, t, is64); d = ld_idx(eidx, E + t, is64); }
    else { s = t - E; d = s; }
    int pos = atomicAdd(&cursor[d], 1);
    sord[rowptr[d] + pos] = s;
}

// ---------------- fused edge phase, H=4: one wave per node ----------------
// lane -> (h = lane>>4, channel quad c0 = (lane&15)*4). Per edge: ONE float4
// gather/lane, 4-shuffle 16-lane reduce, float4 online softmax in log2 domain.

#define SCORE4(p, xv) { float t_;                                   \
    t_ = xv.x + xrv.x; p  = fmaxf(t_, 0.2f * t_) * atv.x;           \
    t_ = xv.y + xrv.y; p += fmaxf(t_, 0.2f * t_) * atv.y;           \
    t_ = xv.z + xrv.z; p += fmaxf(t_, 0.2f * t_) * atv.z;           \
    t_ = xv.w + xrv.w; p += fmaxf(t_, 0.2f * t_) * atv.w; }

#define RED16(p) { p += __shfl_xor(p, 1); p += __shfl_xor(p, 2);    \
                   p += __shfl_xor(p, 4); p += __shfl_xor(p, 8); }

#define ONL(v, xv) { float nm = fmaxf(m, v); float sc = EXP2(m - nm); float ev = EXP2(v - nm); \
    ssum = ssum * sc + ev;                                           \
    o.x = o.x * sc + ev * xv.x; o.y = o.y * sc + ev * xv.y;          \
    o.z = o.z * sc + ev * xv.z; o.w = o.w * sc + ev * xv.w; m = nm; }

__global__ __launch_bounds__(256) void node_attn_h4(
    const float* __restrict__ xl, const float* __restrict__ xr,
    const float* __restrict__ att, const float* __restrict__ bias,
    const int* __restrict__ rowptr, const int* __restrict__ sord, int n,
    unsigned short* __restrict__ outb)
{
    int d = (blockIdx.x * blockDim.x + threadIdx.x) >> 6;
    int lane = threadIdx.x & 63;
    if (d >= n) return;
    int off = (lane >> 4) * 64 + (lane & 15) * 4;  // h*64 + c0
    float4 xrv = *(const float4*)(xr + (size_t)d * 256 + off);
    float4 atv = *(const float4*)(att + off);
    int beg = rowptr[d], end = rowptr[d + 1];
    float m = -1e30f, ssum = 0.f;
    float4 o = {0.f, 0.f, 0.f, 0.f};
    for (int i = beg; i < end; i += 4) {
        int i1 = i + 1, i2 = i + 2, i3 = i + 3;
        int v1 = i1 < end, v2 = i2 < end, v3 = i3 < end;
        int s0 = sord[i];
        int s1 = sord[v1 ? i1 : i];
        int s2 = sord[v2 ? i2 : i];
        int s3 = sord[v3 ? i3 : i];
        float4 x0 = *(const float4*)(xl + (size_t)s0 * 256 + off);
        float4 x1 = *(const float4*)(xl + (size_t)s1 * 256 + off);
        float4 x2 = *(const float4*)(xl + (size_t)s2 * 256 + off);
        float4 x3 = *(const float4*)(xl + (size_t)s3 * 256 + off);
        float p0, p1, p2, p3;
        SCORE4(p0, x0); SCORE4(p1, x1); SCORE4(p2, x2); SCORE4(p3, x3);
        RED16(p0); RED16(p1); RED16(p2); RED16(p3);
        p0 *= LOG2E;
        p1 = v1 ? p1 * LOG2E : -1e30f;
        p2 = v2 ? p2 * LOG2E : -1e30f;
        p3 = v3 ? p3 * LOG2E : -1e30f;
        ONL(p0, x0); ONL(p1, x1); ONL(p2, x2); ONL(p3, x3);
    }
    float inv = 1.f / (ssum + 1e-16f);
    float4 bv = *(const float4*)(bias + off);
    float r0 = o.x * inv + bv.x, r1 = o.y * inv + bv.y;
    float r2 = o.z * inv + bv.z, r3 = o.w * inv + bv.w;
    r0 = fmaxf(r0, 0.01f * r0); r1 = fmaxf(r1, 0.01f * r1);
    r2 = fmaxf(r2, 0.01f * r2); r3 = fmaxf(r3, 0.01f * r3);
    ushort4 ov;
    ov.x = f2bf(r0); ov.y = f2bf(r1); ov.z = f2bf(r2); ov.w = f2bf(r3);
    *(ushort4*)(outb + (size_t)d * 256 + off) = ov;
}

// ---------------- fused edge phase, H=1: one wave per node, 4 edges in flight ----------------
// lane -> (sg = lane>>4 edge slot, c0 = (lane&15)*4). Cross-subgroup merge at end.
__global__ __launch_bounds__(256) void node_attn_h1(
    const float* __restrict__ xl, const float* __restrict__ xr,
    const float* __restrict__ att, const float* __restrict__ bias,
    const int* __restrict__ rowptr, const int* __restrict__ sord, int n,
    float* __restrict__ outf)
{
    int d = (blockIdx.x * blockDim.x + threadIdx.x) >> 6;
    int lane = threadIdx.x & 63;
    if (d >= n) return;
    int sg = lane >> 4, c0 = (lane & 15) * 4;
    float4 xrv = *(const float4*)(xr + (size_t)d * 64 + c0);
    float4 atv = *(const float4*)(att + c0);
    int beg = rowptr[d], end = rowptr[d + 1];
    float m = -1e30f, ssum = 0.f;
    float4 o = {0.f, 0.f, 0.f, 0.f};
    for (int i0 = beg; i0 < end; i0 += 8) {
        int ia = i0 + sg, ib = i0 + 4 + sg;
        int va = ia < end, vb = ib < end;
        int sa = sord[va ? ia : beg];
        int sb = sord[vb ? ib : beg];
        float4 xa = *(const float4*)(xl + (size_t)sa * 64 + c0);
        float4 xb = *(const float4*)(xl + (size_t)sb * 64 + c0);
        float pa, pb;
        SCORE4(pa, xa); SCORE4(pb, xb);
        RED16(pa); RED16(pb);
        pa = va ? pa * LOG2E : -1e30f;
        pb = vb ? pb * LOG2E : -1e30f;
        ONL(pa, xa); ONL(pb, xb);
    }
    // merge the 4 subgroup states (each holds same channels c0..c0+3)
#pragma unroll
    for (int offs = 16; offs <= 32; offs <<= 1) {
        float m2 = __shfl_xor(m, offs);
        float s2 = __shfl_xor(ssum, offs);
        float4 o2;
        o2.x = __shfl_xor(o.x, offs); o2.y = __shfl_xor(o.y, offs);
        o2.z = __shfl_xor(o.z, offs); o2.w = __shfl_xor(o.w, offs);
        float nm = fmaxf(m, m2);
        float sa_ = EXP2(m - nm), sb_ = EXP2(m2 - nm);
        ssum = ssum * sa_ + s2 * sb_;
        o.x = o.x * sa_ + o2.x * sb_; o.y = o.y * sa_ + o2.y * sb_;
        o.z = o.z * sa_ + o2.z * sb_; o.w = o.w * sa_ + o2.w * sb_;
        m = nm;
    }
    if (sg == 0) {
        float inv = 1.f / (ssum + 1e-16f);
        float4 bv = *(const float4*)(bias + c0);
        float4 res;
        res.x = o.x * inv + bv.x; res.y = o.y * inv + bv.y;
        res.z = o.z * inv + bv.z; res.w = o.w * inv + bv.w;
        *(float4*)(outf + (size_t)d * 64 + c0) = res;
    }
}

// fused predict head
__global__ void predict_head(const float* __restrict__ h2,
                             const float* __restrict__ Wp1, const float* __restrict__ bp1,
                             const float* __restrict__ Wp2, const float* __restrict__ bp2,
                             float* __restrict__ logits, int n)
{
    int i = blockIdx.x * blockDim.x + threadIdx.x;
    if (i >= n) return;
    float h[64];
#pragma unroll
    for (int c = 0; c < 64; c++) h[c] = h2[(long long)i * 64 + c];
    float logit = bp2[0];
#pragma unroll
    for (int j = 0; j < 32; j++) {
        float z = bp1[j];
#pragma unroll
        for (int c = 0; c < 64; c++) z += h[c] * Wp1[c * 32 + j];
        z = lrelu(z, 0.01f);
        logit += z * Wp2[j];
    }
    logits[i] = logit;
}

extern "C" void kernel_launch(void* const* d_in, const int* in_sizes, int n_in,
                              void* d_out, int out_size, void* d_ws, size_t ws_size,
                              hipStream_t stream)
{
    const float* x    = (const float*)d_in[0];
    const int*   eidx = (const int*)d_in[1];
    const float* W1l  = (const float*)d_in[2];
    const float* b1l  = (const float*)d_in[3];
    const float* W1r  = (const float*)d_in[4];
    const float* b1r  = (const float*)d_in[5];
    const float* att1 = (const float*)d_in[6];
    const float* bias1= (const float*)d_in[7];
    const float* W2l  = (const float*)d_in[8];
    const float* b2l  = (const float*)d_in[9];
    const float* W2r  = (const float*)d_in[10];
    const float* b2r  = (const float*)d_in[11];
    const float* att2 = (const float*)d_in[12];
    const float* bias2= (const float*)d_in[13];
    const float* Wp1  = (const float*)d_in[14];
    const float* bp1  = (const float*)d_in[15];
    const float* Wp2  = (const float*)d_in[16];
    const float* bp2  = (const float*)d_in[17];

    const int n = in_sizes[0] / 256;  // 50000
    const int E = in_sizes[1] / 2;    // 600000
    const int Etot = E + n;

    float* out = (float*)d_out;       // [0,n): logits ; [n, n+n*64): h
    float* ws  = (float*)d_ws;

    // workspace layout
    float*          xl1   = ws;                                        // n*256 f32
    float*          xr1   = xl1 + (size_t)n * 256;                     // n*256 f32
    unsigned short* xb    = (unsigned short*)(xr1 + (size_t)n * 256);  // n*256 bf16 (reused as h1b)
    unsigned short* w1lt  = xb + (size_t)n * 256;                      // 256*256
    unsigned short* w1rt  = w1lt + 65536;
    unsigned short* w2lt  = w1rt + 65536;                              // 64*256
    unsigned short* w2rt  = w2lt + 16384;
    int*            rowptr= (int*)(w2rt + 16384);                      // n+1
    int*            cnt   = rowptr + (n + 1);                          // n
    int*            sord  = cnt + n;                                   // Etot
    int*            flagp = sord + Etot;
    float*          xl2   = xl1;                                       // n*64 (reuse)
    float*          xr2   = xl1 + (size_t)n * 64;
    unsigned short* h1b   = xb;                                        // reuse after gemm1
    float*          h2    = out + n;

    detect_i64<<<1, 64, 0, stream>>>((const unsigned int*)eidx, flagp);

    // ---- CSR build ----
    hipMemsetAsync(cnt, 0, (size_t)n * sizeof(int), stream);
    hist_dst<<<(Etot + 255) / 256, 256, 0, stream>>>(eidx, flagp, E, n, cnt);
    scan_excl<<<1, 1024, 0, stream>>>(cnt, rowptr, n);
    hipMemsetAsync(cnt, 0, (size_t)n * sizeof(int), stream);
    scatter_edges<<<(Etot + 255) / 256, 256, 0, stream>>>(eidx, flagp, E, n, rowptr, cnt, sord);

    // ---- conversions ----
    {
        long long tot = (long long)n * 256;
        f32_to_bf16_vec<<<(int)((tot / 4 + 255) / 256), 256, 0, stream>>>(x, xb, tot);
        transpose_bf16<<<(256 * 256 + 255) / 256, 256, 0, stream>>>(W1l, w1lt, 256, 256);
        transpose_bf16<<<(256 * 256 + 255) / 256, 256, 0, stream>>>(W1r, w1rt, 256, 256);
        transpose_bf16<<<(256 * 64 + 255) / 256, 256, 0, stream>>>(W2l, w2lt, 256, 64);
        transpose_bf16<<<(256 * 64 + 255) / 256, 256, 0, stream>>>(W2r, w2rt, 256, 64);
    }

    // ---- layer 1 projections (bf16 MFMA) ----
    {
        dim3 grid((n + 63) / 64, 4);
        gemm_mfma<<<grid, 256, 0, stream>>>(xb, w1lt, b1l, xl1, n, 256, 256);
        gemm_mfma<<<grid, 256, 0, stream>>>(xb, w1rt, b1r, xr1, n, 256, 256);
    }

    // ---- layer 1 edge phase (fused, one wave per node, bias + leaky 0.01) ----
    node_attn_h4<<<(n + 3) / 4, 256, 0, stream>>>(xl1, xr1, att1, bias1, rowptr, sord, n, h1b);

    // ---- layer 2 projections ----
    {
        dim3 grid((n + 63) / 64, 1);
        gemm_mfma<<<grid, 256, 0, stream>>>(h1b, w2lt, b2l, xl2, n, 64, 256);
        gemm_mfma<<<grid, 256, 0, stream>>>(h1b, w2rt, b2r, xr2, n, 64, 256);
    }

    // ---- layer 2 edge phase ----
    node_attn_h1<<<(n + 3) / 4, 256, 0, stream>>>(xl2, xr2, att2, bias2, rowptr, sord, n, h2);

    // ---- predict head ----
    predict_head<<<(n + 255) / 256, 256, 0, stream>>>(h2, Wp1, bp1, Wp2, bp2, out, n);
}

// Round 7
// 334.067 us; speedup vs baseline: 5.4629x; 1.3979x over previous
//
#include <hip/hip_runtime.h>

typedef __attribute__((ext_vector_type(8))) __bf16 bf16x8;
typedef __attribute__((ext_vector_type(4))) float f32x4;

#define EXP2 __builtin_amdgcn_exp2f
#define LOG2E 1.44269504f

__device__ __forceinline__ float lrelu(float v, float s) { return v > 0.f ? v : v * s; }

__device__ __forceinline__ unsigned short f2bf(float f) {
    unsigned int u = __float_as_uint(f);
    u += 0x7FFFu + ((u >> 16) & 1u);
    return (unsigned short)(u >> 16);
}
__device__ __forceinline__ float bf2f(unsigned short u) {
    return __uint_as_float((unsigned int)u << 16);
}

__device__ __forceinline__ int ld_idx(const int* p, int e, int is64) {
    return is64 ? (int)(((const long long*)p)[e]) : p[e];
}

__global__ void detect_i64(const unsigned int* idx, int* flag) {
    if (blockIdx.x == 0 && threadIdx.x == 0) {
        int all0 = 1;
        for (int i = 1; i < 256; i += 2) {
            if (idx[i] != 0u) { all0 = 0; break; }
        }
        *flag = all0;
    }
}

// ---------------- conversions ----------------
__global__ void f32_to_bf16_vec(const float* __restrict__ in, unsigned short* __restrict__ out,
                                long long total)
{
    long long i = ((long long)blockIdx.x * blockDim.x + threadIdx.x) * 4;
    if (i + 4 <= total) {
        float4 v = *(const float4*)(in + i);
        ushort4 o;
        o.x = f2bf(v.x); o.y = f2bf(v.y); o.z = f2bf(v.z); o.w = f2bf(v.w);
        *(ushort4*)(out + i) = o;
    } else {
        for (; i < total; i++) out[i] = f2bf(in[i]);
    }
}

// builds w1t [512][256] = concat(W1l^T, W1r^T), w2t [128][256] = concat(W2l^T, W2r^T)
__global__ void prep_weights(const float* __restrict__ W1l, const float* __restrict__ W1r,
                             const float* __restrict__ W2l, const float* __restrict__ W2r,
                             unsigned short* __restrict__ w1t, unsigned short* __restrict__ w2t)
{
    int t = blockIdx.x * blockDim.x + threadIdx.x;
    if (t < 131072) {
        int nn = t >> 8, k = t & 255;
        float v = (nn < 256) ? W1l[k * 256 + nn] : W1r[k * 256 + (nn - 256)];
        w1t[t] = f2bf(v);
    } else if (t < 163840) {
        int u = t - 131072;
        int nn = u >> 8, k = u & 255;
        float v = (nn < 64) ? W2l[k * 64 + nn] : W2r[k * 64 + (nn - 64)];
        w2t[u] = f2bf(v);
    }
}

// ---------------- bf16 MFMA GEMM: C[M,N](bf16) = A[M,K] @ Bt[N,K]^T + bias ----------------
__global__ __launch_bounds__(256) void gemm_mfma(
    const unsigned short* __restrict__ A,   // [M,K] bf16
    const unsigned short* __restrict__ Bt,  // [N,K] bf16
    const float* __restrict__ biasL, const float* __restrict__ biasR, int NL,
    unsigned short* __restrict__ C, int M, int N, int K)
{
    int wid = threadIdx.x >> 6;
    int lane = threadIdx.x & 63;
    int wm = wid >> 1, wn = wid & 1;
    int bm = blockIdx.x * 64, bn = blockIdx.y * 64;
    int r16 = lane & 15, kg = lane >> 4;
    f32x4 acc[2][2] = {};
    const int rowA0 = bm + wm * 32 + r16;
    const int rowB0 = bn + wn * 32 + r16;
    for (int k0 = 0; k0 < K; k0 += 32) {
        int kofs = k0 + kg * 8;
        bf16x8 a[2], b[2];
#pragma unroll
        for (int f = 0; f < 2; f++) {
            int ra = rowA0 + 16 * f;
            ra = (ra < M) ? ra : 0;
            a[f] = *(const bf16x8*)(A + (size_t)ra * K + kofs);
            b[f] = *(const bf16x8*)(Bt + (size_t)(rowB0 + 16 * f) * K + kofs);
        }
#pragma unroll
        for (int i = 0; i < 2; i++)
#pragma unroll
            for (int j = 0; j < 2; j++)
                acc[i][j] = __builtin_amdgcn_mfma_f32_16x16x32_bf16(a[i], b[j], acc[i][j], 0, 0, 0);
    }
    int crow = (lane >> 4) * 4;
    int ccol = lane & 15;
#pragma unroll
    for (int i = 0; i < 2; i++) {
#pragma unroll
        for (int j = 0; j < 2; j++) {
            int col = bn + wn * 32 + j * 16 + ccol;
            float bv = (col < NL) ? biasL[col] : biasR[col - NL];
#pragma unroll
            for (int r = 0; r < 4; r++) {
                int row = bm + wm * 32 + i * 16 + crow + r;
                if (row < M) C[(size_t)row * N + col] = f2bf(acc[i][j][r] + bv);
            }
        }
    }
}

// ---------------- CSR build ----------------
__global__ void hist_dst(const int* __restrict__ eidx, const int* __restrict__ flagp,
                         int E, int n, int* __restrict__ cnt)
{
    int t = blockIdx.x * blockDim.x + threadIdx.x;
    if (t >= E + n) return;
    int is64 = *flagp;
    int d = (t < E) ? ld_idx(eidx, E + t, is64) : (t - E);
    atomicAdd(&cnt[d], 1);
}

// multi-block exclusive scan: scan1 (per-block) -> scan2 (block sums) -> scan3 (add offsets)
__global__ __launch_bounds__(1024) void scan1(const int* __restrict__ cnt,
                                              int* __restrict__ rowptr, int* __restrict__ psum, int n)
{
    __shared__ int wsum[16];
    int tid = threadIdx.x, lane = tid & 63, w = tid >> 6;
    int gid = blockIdx.x * 1024 + tid;
    int v = (gid < n) ? cnt[gid] : 0;
    int sc = v;
#pragma unroll
    for (int o = 1; o < 64; o <<= 1) { int t2 = __shfl_up(sc, o); if (lane >= o) sc += t2; }
    if (lane == 63) wsum[w] = sc;
    __syncthreads();
    if (tid < 16) {
        int t2 = wsum[tid];
#pragma unroll
        for (int o = 1; o < 16; o <<= 1) { int u = __shfl_up(t2, o); if (tid >= o) t2 += u; }
        wsum[tid] = t2;
    }
    __syncthreads();
    int wofs = w ? wsum[w - 1] : 0;
    if (gid < n) rowptr[gid] = wofs + sc - v;
    if (tid == 1023) psum[blockIdx.x] = wsum[15];
}

__global__ void scan2(const int* __restrict__ psum, int* __restrict__ pofs,
                      int* __restrict__ rowptr_n, int nb)
{
    int lane = threadIdx.x;
    int v = (lane < nb) ? psum[lane] : 0;
    int sc = v;
#pragma unroll
    for (int o = 1; o < 64; o <<= 1) { int t = __shfl_up(sc, o); if (lane >= o) sc += t; }
    if (lane < nb) pofs[lane] = sc - v;
    if (lane == 63) *rowptr_n = sc;
}

__global__ __launch_bounds__(1024) void scan3(int* __restrict__ rowptr,
                                              const int* __restrict__ pofs, int n)
{
    int gid = blockIdx.x * 1024 + threadIdx.x;
    if (gid < n) rowptr[gid] += pofs[blockIdx.x];
}

__global__ void scatter_edges(const int* __restrict__ eidx, const int* __restrict__ flagp,
                              int E, int n, const int* __restrict__ rowptr,
                              int* __restrict__ cursor, int* __restrict__ sord)
{
    int t = blockIdx.x * blockDim.x + threadIdx.x;
    if (t >= E + n) return;
    int is64 = *flagp;
    int s, d;
    if (t < E) { s = ld_idx(eidx, t, is64); d = ld_idx(eidx, E + t, is64); }
    else { s = t - E; d = s; }
    int pos = atomicAdd(&cursor[d], 1);
    sord[rowptr[d] + pos] = s;
}

// ---------------- fused edge phase, H=4: one wave per node, bf16 xlr[n][512] ----------------
#define SCORE4(p, xv) { float t_;                                   \
    t_ = xv.x + xrv.x; p  = fmaxf(t_, 0.2f * t_) * atv.x;           \
    t_ = xv.y + xrv.y; p += fmaxf(t_, 0.2f * t_) * atv.y;           \
    t_ = xv.z + xrv.z; p += fmaxf(t_, 0.2f * t_) * atv.z;           \
    t_ = xv.w + xrv.w; p += fmaxf(t_, 0.2f * t_) * atv.w; }

#define RED16(p) { p += __shfl_xor(p, 1); p += __shfl_xor(p, 2);    \
                   p += __shfl_xor(p, 4); p += __shfl_xor(p, 8); }

#define ONL(v, xv) { float nm = fmaxf(m, v); float sc = EXP2(m - nm); float ev = EXP2(v - nm); \
    ssum = ssum * sc + ev;                                           \
    o.x = o.x * sc + ev * xv.x; o.y = o.y * sc + ev * xv.y;          \
    o.z = o.z * sc + ev * xv.z; o.w = o.w * sc + ev * xv.w; m = nm; }

#define CVT4(f, u) float4 f = { bf2f(u.x), bf2f(u.y), bf2f(u.z), bf2f(u.w) };

__global__ __launch_bounds__(256) void node_attn_h4(
    const unsigned short* __restrict__ xlr,  // [n][512]: cols 0-255 = xl, 256-511 = xr
    const float* __restrict__ att, const float* __restrict__ bias,
    const int* __restrict__ rowptr, const int* __restrict__ sord, int n,
    unsigned short* __restrict__ outb)
{
    int d = (blockIdx.x * blockDim.x + threadIdx.x) >> 6;
    int lane = threadIdx.x & 63;
    if (d >= n) return;
    int off = (lane >> 4) * 64 + (lane & 15) * 4;  // h*64 + c0
    ushort4 xru = *(const ushort4*)(xlr + (size_t)d * 512 + 256 + off);
    CVT4(xrv, xru);
    float4 atv = *(const float4*)(att + off);
    int beg = rowptr[d], end = rowptr[d + 1];
    float m = -1e30f, ssum = 0.f;
    float4 o = {0.f, 0.f, 0.f, 0.f};
    for (int i = beg; i < end; i += 4) {
        int i1 = i + 1, i2 = i + 2, i3 = i + 3;
        int v1 = i1 < end, v2 = i2 < end, v3 = i3 < end;
        int s0 = sord[i];
        int s1 = sord[v1 ? i1 : i];
        int s2 = sord[v2 ? i2 : i];
        int s3 = sord[v3 ? i3 : i];
        ushort4 u0 = *(const ushort4*)(xlr + (size_t)s0 * 512 + off);
        ushort4 u1 = *(const ushort4*)(xlr + (size_t)s1 * 512 + off);
        ushort4 u2 = *(const ushort4*)(xlr + (size_t)s2 * 512 + off);
        ushort4 u3 = *(const ushort4*)(xlr + (size_t)s3 * 512 + off);
        CVT4(x0, u0); CVT4(x1, u1); CVT4(x2, u2); CVT4(x3, u3);
        float p0, p1, p2, p3;
        SCORE4(p0, x0); SCORE4(p1, x1); SCORE4(p2, x2); SCORE4(p3, x3);
        RED16(p0); RED16(p1); RED16(p2); RED16(p3);
        p0 *= LOG2E;
        p1 = v1 ? p1 * LOG2E : -1e30f;
        p2 = v2 ? p2 * LOG2E : -1e30f;
        p3 = v3 ? p3 * LOG2E : -1e30f;
        ONL(p0, x0); ONL(p1, x1); ONL(p2, x2); ONL(p3, x3);
    }
    float inv = 1.f / (ssum + 1e-16f);
    float4 bv = *(const float4*)(bias + off);
    float r0 = o.x * inv + bv.x, r1 = o.y * inv + bv.y;
    float r2 = o.z * inv + bv.z, r3 = o.w * inv + bv.w;
    r0 = fmaxf(r0, 0.01f * r0); r1 = fmaxf(r1, 0.01f * r1);
    r2 = fmaxf(r2, 0.01f * r2); r3 = fmaxf(r3, 0.01f * r3);
    ushort4 ov;
    ov.x = f2bf(r0); ov.y = f2bf(r1); ov.z = f2bf(r2); ov.w = f2bf(r3);
    *(ushort4*)(outb + (size_t)d * 256 + off) = ov;
}

// ---------------- fused edge phase, H=1: bf16 xlr2[n][128], 4+4 edges in flight ----------------
__global__ __launch_bounds__(256) void node_attn_h1(
    const unsigned short* __restrict__ xlr,  // [n][128]: 0-63 = xl, 64-127 = xr
    const float* __restrict__ att, const float* __restrict__ bias,
    const int* __restrict__ rowptr, const int* __restrict__ sord, int n,
    float* __restrict__ outf)
{
    int d = (blockIdx.x * blockDim.x + threadIdx.x) >> 6;
    int lane = threadIdx.x & 63;
    if (d >= n) return;
    int sg = lane >> 4, c0 = (lane & 15) * 4;
    ushort4 xru = *(const ushort4*)(xlr + (size_t)d * 128 + 64 + c0);
    CVT4(xrv, xru);
    float4 atv = *(const float4*)(att + c0);
    int beg = rowptr[d], end = rowptr[d + 1];
    float m = -1e30f, ssum = 0.f;
    float4 o = {0.f, 0.f, 0.f, 0.f};
    for (int i0 = beg; i0 < end; i0 += 8) {
        int ia = i0 + sg, ib = i0 + 4 + sg;
        int va = ia < end, vb = ib < end;
        int sa = sord[va ? ia : beg];
        int sb = sord[vb ? ib : beg];
        ushort4 ua = *(const ushort4*)(xlr + (size_t)sa * 128 + c0);
        ushort4 ub = *(const ushort4*)(xlr + (size_t)sb * 128 + c0);
        CVT4(xa, ua); CVT4(xb, ub);
        float pa, pb;
        SCORE4(pa, xa); SCORE4(pb, xb);
        RED16(pa); RED16(pb);
        pa = va ? pa * LOG2E : -1e30f;
        pb = vb ? pb * LOG2E : -1e30f;
        ONL(pa, xa); ONL(pb, xb);
    }
#pragma unroll
    for (int offs = 16; offs <= 32; offs <<= 1) {
        float m2 = __shfl_xor(m, offs);
        float s2 = __shfl_xor(ssum, offs);
        float4 o2;
        o2.x = __shfl_xor(o.x, offs); o2.y = __shfl_xor(o.y, offs);
        o2.z = __shfl_xor(o.z, offs); o2.w = __shfl_xor(o.w, offs);
        float nm = fmaxf(m, m2);
        float sa_ = EXP2(m - nm), sb_ = EXP2(m2 - nm);
        ssum = ssum * sa_ + s2 * sb_;
        o.x = o.x * sa_ + o2.x * sb_; o.y = o.y * sa_ + o2.y * sb_;
        o.z = o.z * sa_ + o2.z * sb_; o.w = o.w * sa_ + o2.w * sb_;
        m = nm;
    }
    if (sg == 0) {
        float inv = 1.f / (ssum + 1e-16f);
        float4 bv = *(const float4*)(bias + c0);
        float4 res;
        res.x = o.x * inv + bv.x; res.y = o.y * inv + bv.y;
        res.z = o.z * inv + bv.z; res.w = o.w * inv + bv.w;
        *(float4*)(outf + (size_t)d * 64 + c0) = res;
    }
}

// fused predict head
__global__ void predict_head(const float* __restrict__ h2,
                             const float* __restrict__ Wp1, const float* __restrict__ bp1,
                             const float* __restrict__ Wp2, const float* __restrict__ bp2,
                             float* __restrict__ logits, int n)
{
    int i = blockIdx.x * blockDim.x + threadIdx.x;
    if (i >= n) return;
    float h[64];
#pragma unroll
    for (int c = 0; c < 64; c++) h[c] = h2[(long long)i * 64 + c];
    float logit = bp2[0];
#pragma unroll
    for (int j = 0; j < 32; j++) {
        float z = bp1[j];
#pragma unroll
        for (int c = 0; c < 64; c++) z += h[c] * Wp1[c * 32 + j];
        z = lrelu(z, 0.01f);
        logit += z * Wp2[j];
    }
    logits[i] = logit;
}

extern "C" void kernel_launch(void* const* d_in, const int* in_sizes, int n_in,
                              void* d_out, int out_size, void* d_ws, size_t ws_size,
                              hipStream_t stream)
{
    const float* x    = (const float*)d_in[0];
    const int*   eidx = (const int*)d_in[1];
    const float* W1l  = (const float*)d_in[2];
    const float* b1l  = (const float*)d_in[3];
    const float* W1r  = (const float*)d_in[4];
    const float* b1r  = (const float*)d_in[5];
    const float* att1 = (const float*)d_in[6];
    const float* bias1= (const float*)d_in[7];
    const float* W2l  = (const float*)d_in[8];
    const float* b2l  = (const float*)d_in[9];
    const float* W2r  = (const float*)d_in[10];
    const float* b2r  = (const float*)d_in[11];
    const float* att2 = (const float*)d_in[12];
    const float* bias2= (const float*)d_in[13];
    const float* Wp1  = (const float*)d_in[14];
    const float* bp1  = (const float*)d_in[15];
    const float* Wp2  = (const float*)d_in[16];
    const float* bp2  = (const float*)d_in[17];

    const int n = in_sizes[0] / 256;  // 50000
    const int E = in_sizes[1] / 2;    // 600000
    const int Etot = E + n;
    const int nb = (n + 1023) / 1024; // scan blocks (<=64 for n<=65536)

    float* out = (float*)d_out;       // [0,n): logits ; [n, n+n*64): h
    unsigned short* ws16 = (unsigned short*)d_ws;

    // workspace layout (shorts)
    unsigned short* xb    = ws16;                       // n*256 bf16 (aliased: h1b)
    unsigned short* xlr1  = xb + (size_t)n * 256;       // n*512 bf16 (aliased: xlr2)
    unsigned short* w1t   = xlr1 + (size_t)n * 512;     // 512*256
    unsigned short* w2t   = w1t + 131072;               // 128*256
    int*            rowptr= (int*)(w2t + 32768);        // n+1
    int*            cnt   = rowptr + (n + 1);           // n
    int*            sord  = cnt + n;                    // Etot
    int*            psum  = sord + Etot;                // 64
    int*            pofs  = psum + 64;                  // 64
    int*            flagp = pofs + 64;                  // 1
    unsigned short* h1b   = xb;                         // attn1 out, gemm2 in
    unsigned short* xlr2  = xlr1;                       // n*128 bf16
    float*          h2    = out + n;

    detect_i64<<<1, 64, 0, stream>>>((const unsigned int*)eidx, flagp);

    // ---- CSR build ----
    hipMemsetAsync(cnt, 0, (size_t)n * sizeof(int), stream);
    hist_dst<<<(Etot + 255) / 256, 256, 0, stream>>>(eidx, flagp, E, n, cnt);
    scan1<<<nb, 1024, 0, stream>>>(cnt, rowptr, psum, n);
    scan2<<<1, 64, 0, stream>>>(psum, pofs, rowptr + n, nb);
    scan3<<<nb, 1024, 0, stream>>>(rowptr, pofs, n);
    hipMemsetAsync(cnt, 0, (size_t)n * sizeof(int), stream);
    scatter_edges<<<(Etot + 255) / 256, 256, 0, stream>>>(eidx, flagp, E, n, rowptr, cnt, sord);

    // ---- conversions ----
    {
        long long tot = (long long)n * 256;
        f32_to_bf16_vec<<<(int)((tot / 4 + 255) / 256), 256, 0, stream>>>(x, xb, tot);
        prep_weights<<<(163840 + 255) / 256, 256, 0, stream>>>(W1l, W1r, W2l, W2r, w1t, w2t);
    }

    // ---- layer 1 projection (fused l|r, bf16 out) ----
    {
        dim3 grid((n + 63) / 64, 8);
        gemm_mfma<<<grid, 256, 0, stream>>>(xb, w1t, b1l, b1r, 256, xlr1, n, 512, 256);
    }

    // ---- layer 1 edge phase ----
    node_attn_h4<<<(n + 3) / 4, 256, 0, stream>>>(xlr1, att1, bias1, rowptr, sord, n, h1b);

    // ---- layer 2 projection ----
    {
        dim3 grid((n + 63) / 64, 2);
        gemm_mfma<<<grid, 256, 0, stream>>>(h1b, w2t, b2l, b2r, 64, xlr2, n, 128, 256);
    }

    // ---- layer 2 edge phase ----
    node_attn_h1<<<(n + 3) / 4, 256, 0, stream>>>(xlr2, att2, bias2, rowptr, sord, n, h2);

    // ---- predict head ----
    predict_head<<<(n + 255) / 256, 256, 0, stream>>>(h2, Wp1, bp1, Wp2, bp2, out, n);
}